// Round 4
// baseline (252.401 us; speedup 1.0000x reference)
//
#include <hip/hip_runtime.h>

typedef unsigned short u16;
typedef unsigned int u32;
typedef unsigned long long u64;
typedef __attribute__((ext_vector_type(8))) short short8;
typedef __attribute__((ext_vector_type(4))) float f32x4;

#define ICAPS 512
#define IDIM 128
#define NFLAT 512  // NCAPS(16) * ODIM(32)

__device__ __forceinline__ float b2f(u16 h) {
    union { u32 u; float f; } x; x.u = ((u32)h) << 16; return x.f;
}
__device__ __forceinline__ u16 f2b(float f) {
    union { float f; u32 u; } x; x.f = f;
    return (u16)((x.u + 0x7FFFu + ((x.u >> 16) & 1u)) >> 16);
}

// Classify d_in[0] dtype: bf16 => every u16 is a bf16 of ~N(0,1) (exponent
// field in [100,140]); fp32 => even u16s are mantissa words (random exponent
// field, ~16% plausible). count>420 of 512 => bf16.
__global__ __launch_bounds__(256) void probe_kernel(const u16* __restrict__ xs,
                                                    int* __restrict__ flag) {
    __shared__ int cnt[256];
    const int t = threadIdx.x;
    int c = 0;
    #pragma unroll
    for (int k = 0; k < 2; ++k) {
        u16 h = xs[t * 2 + k];
        int e = (h >> 7) & 0xFF;
        c += (e >= 100 && e <= 140) ? 1 : 0;
    }
    cnt[t] = c;
    __syncthreads();
    for (int s = 128; s > 0; s >>= 1) {
        if (t < s) cnt[t] += cnt[t + s];
        __syncthreads();
    }
    if (t == 0) *flag = (cnt[0] > 420) ? 1 : 0;
}

// u_hat[b,i,n] = sum_k x[b,i,k] * W[i, j(n), k, d(n)],  n = j*32+d
// Block: one i, one 128-wide n-chunk. M=64, N=128, K=128.
__global__ __launch_bounds__(256) void gemm_kernel(const void* __restrict__ xv,
                                                   const void* __restrict__ Wv,
                                                   u16* __restrict__ uhat,
                                                   const int* __restrict__ flagp) {
    __shared__ __align__(16) u16 As[64 * 136];   // x[b][k], pitch 136
    __shared__ __align__(16) u16 Bs[128 * 136];  // W^T as [n][k], pitch 136
    const int bx = blockIdx.x;
    const int i = bx >> 2;
    const int chunk = bx & 3;
    const int t = threadIdx.x;
    const int fl = *flagp;   // uniform

    if (fl) {
        // ---- bf16 input staging ----
        const u16* x = (const u16*)xv;
        const u16* W = (const u16*)Wv;
        const uint4* xa = (const uint4*)x;
        #pragma unroll
        for (int l = 0; l < 4; ++l) {
            int id = l * 256 + t;           // 0..1023
            int row = id >> 4, c16 = id & 15;
            uint4 v = xa[row * (ICAPS * IDIM / 8) + i * (IDIM / 8) + c16];
            *(uint4*)&As[row * 136 + c16 * 8] = v;
        }
        const uint4* wb = (const uint4*)W + (size_t)(i * 16 + chunk * 4) * (IDIM * 32 / 8);
        #pragma unroll
        for (int l = 0; l < 8; ++l) {
            int id = l * 256 + t;           // 0..2047
            union { uint4 v; u16 h[8]; } tmp; tmp.v = wb[id];
            int e = id * 8;
            int jj = e >> 12;
            int k = (e & 4095) >> 5;
            int db = e & 31;                // multiple of 8
            int nb = jj * 32 + db;
            #pragma unroll
            for (int m = 0; m < 8; ++m) Bs[(nb + m) * 136 + k] = tmp.h[m];
        }
    } else {
        // ---- fp32 input staging (convert to bf16) ----
        const float4* xa = (const float4*)xv;
        #pragma unroll
        for (int l = 0; l < 8; ++l) {
            int id = l * 256 + t;           // 0..2047
            int row = id >> 5, kq = id & 31;
            float4 v = xa[row * (ICAPS * IDIM / 4) + i * (IDIM / 4) + kq];
            union { u16 h[4]; u64 q; } pk;
            pk.h[0] = f2b(v.x); pk.h[1] = f2b(v.y);
            pk.h[2] = f2b(v.z); pk.h[3] = f2b(v.w);
            *(u64*)&As[row * 136 + kq * 4] = pk.q;
        }
        const float4* wb = (const float4*)Wv + (size_t)(i * 16 + chunk * 4) * (IDIM * 32 / 4);
        #pragma unroll
        for (int l = 0; l < 16; ++l) {
            int id = l * 256 + t;           // 0..4095
            float4 v = wb[id];
            int e = id * 4;
            int jj = e >> 12;
            int k = (e & 4095) >> 5;
            int db = e & 31;                // multiple of 4
            int nb = jj * 32 + db;
            Bs[(nb + 0) * 136 + k] = f2b(v.x);
            Bs[(nb + 1) * 136 + k] = f2b(v.y);
            Bs[(nb + 2) * 136 + k] = f2b(v.z);
            Bs[(nb + 3) * 136 + k] = f2b(v.w);
        }
    }
    __syncthreads();

    const int lane = t & 63;
    const int w = t >> 6;
    const int ln = lane & 15;
    const int q = lane >> 4;
    f32x4 acc[4][2] = {};
    #pragma unroll
    for (int ks = 0; ks < 4; ++ks) {
        const int ko = ks * 32 + q * 8;
        short8 a[4], bb[2];
        #pragma unroll
        for (int mt = 0; mt < 4; ++mt)
            a[mt] = *(const short8*)&As[(mt * 16 + ln) * 136 + ko];
        #pragma unroll
        for (int nt = 0; nt < 2; ++nt)
            bb[nt] = *(const short8*)&Bs[((2 * w + nt) * 16 + ln) * 136 + ko];
        #pragma unroll
        for (int mt = 0; mt < 4; ++mt)
            #pragma unroll
            for (int nt = 0; nt < 2; ++nt)
                acc[mt][nt] = __builtin_amdgcn_mfma_f32_16x16x32_bf16(a[mt], bb[nt], acc[mt][nt], 0, 0, 0);
    }
    // C/D: col = lane&15, row = q*4 + reg  (m89/m91-verified)
    #pragma unroll
    for (int mt = 0; mt < 4; ++mt)
        #pragma unroll
        for (int nt = 0; nt < 2; ++nt) {
            int n = chunk * 128 + (2 * w + nt) * 16 + ln;
            #pragma unroll
            for (int r = 0; r < 4; ++r) {
                int brow = mt * 16 + q * 4 + r;
                uhat[((size_t)brow * ICAPS + i) * NFLAT + n] = f2b(acc[mt][nt][r]);
            }
        }
}

// s0[b,n] += sum_{i in chunk} u_hat[b,i,n]   (16 chunks per b, global atomics)
__global__ __launch_bounds__(256) void p0_kernel(const u16* __restrict__ uhat,
                                                 float* __restrict__ s0) {
    __shared__ __align__(16) float red4[4][512];
    const int b = blockIdx.x >> 4;
    const int ch = blockIdx.x & 15;
    const int t = threadIdx.x;
    const int wv = t >> 6, l = t & 63;
    float acc[8] = {0.f, 0.f, 0.f, 0.f, 0.f, 0.f, 0.f, 0.f};
    for (int ii = 0; ii < 8; ++ii) {
        int i = ch * 32 + wv * 8 + ii;
        union { uint4 v; u16 h[8]; } tmp;
        tmp.v = *(const uint4*)&uhat[((size_t)b * ICAPS + i) * NFLAT + l * 8];
        #pragma unroll
        for (int e = 0; e < 8; ++e) acc[e] += b2f(tmp.h[e]);
    }
    #pragma unroll
    for (int e = 0; e < 8; ++e) red4[wv][l * 8 + e] = acc[e];
    __syncthreads();
    float v0 = red4[0][t] + red4[1][t] + red4[2][t] + red4[3][t];
    float v1 = red4[0][t + 256] + red4[1][t + 256] + red4[2][t + 256] + red4[3][t + 256];
    atomicAdd(&s0[b * NFLAT + t], v0);
    atomicAdd(&s0[b * NFLAT + t + 256], v1);
}

// One routing pass: osum = squash(s0/16) (+ squash(s1) if use1);
// per (b,i): delta_j = dot_d(osum, u_hat); c = softmax_j(delta); sout += c*u_hat
__global__ __launch_bounds__(256) void route_kernel(const u16* __restrict__ uhat,
                                                    const float* __restrict__ s0,
                                                    const float* __restrict__ s1,
                                                    float* __restrict__ sout,
                                                    int use1) {
    __shared__ __align__(16) float osum[512];
    __shared__ __align__(16) float red4[4][512];
    const int b = blockIdx.x >> 4;
    const int ch = blockIdx.x & 15;
    const int t = threadIdx.x;
    {
        const int j = t >> 4, g = t & 15;   // 16 threads per j, 2 d's each
        const int n0 = j * 32 + 2 * g;
        float v0 = s0[b * NFLAT + n0] * 0.0625f;
        float v1 = s0[b * NFLAT + n0 + 1] * 0.0625f;
        float p = v0 * v0 + v1 * v1;
        p += __shfl_xor(p, 1); p += __shfl_xor(p, 2);
        p += __shfl_xor(p, 4); p += __shfl_xor(p, 8);
        float sc = (p / (1.f + p)) / sqrtf(p + 1e-7f);
        float o0 = sc * v0, o1 = sc * v1;
        if (use1) {
            float w0 = s1[b * NFLAT + n0];
            float w1 = s1[b * NFLAT + n0 + 1];
            float pq = w0 * w0 + w1 * w1;
            pq += __shfl_xor(pq, 1); pq += __shfl_xor(pq, 2);
            pq += __shfl_xor(pq, 4); pq += __shfl_xor(pq, 8);
            float sc1 = (pq / (1.f + pq)) / sqrtf(pq + 1e-7f);
            o0 += sc1 * w0; o1 += sc1 * w1;
        }
        osum[n0] = o0; osum[n0 + 1] = o1;
    }
    __syncthreads();
    const int wv = t >> 6, l = t & 63;
    float os[8], acc[8];
    #pragma unroll
    for (int e = 0; e < 8; ++e) { os[e] = osum[l * 8 + e]; acc[e] = 0.f; }
    for (int ii = 0; ii < 8; ++ii) {
        int i = ch * 32 + wv * 8 + ii;
        union { uint4 v; u16 h[8]; } tmp;
        tmp.v = *(const uint4*)&uhat[((size_t)b * ICAPS + i) * NFLAT + l * 8];
        float u[8];
        #pragma unroll
        for (int e = 0; e < 8; ++e) u[e] = b2f(tmp.h[e]);
        float d = 0.f;
        #pragma unroll
        for (int e = 0; e < 8; ++e) d += u[e] * os[e];
        // lane owns 8 d's; quad (4 lanes) covers one j (32 d's); j = l>>2
        d += __shfl_xor(d, 1); d += __shfl_xor(d, 2);
        float mx = d;
        mx = fmaxf(mx, __shfl_xor(mx, 4));  mx = fmaxf(mx, __shfl_xor(mx, 8));
        mx = fmaxf(mx, __shfl_xor(mx, 16)); mx = fmaxf(mx, __shfl_xor(mx, 32));
        float ex = __expf(d - mx);
        float ss = ex;
        ss += __shfl_xor(ss, 4);  ss += __shfl_xor(ss, 8);
        ss += __shfl_xor(ss, 16); ss += __shfl_xor(ss, 32);
        float c = ex / ss;
        #pragma unroll
        for (int e = 0; e < 8; ++e) acc[e] += c * u[e];
    }
    #pragma unroll
    for (int e = 0; e < 8; ++e) red4[wv][l * 8 + e] = acc[e];
    __syncthreads();
    float v0 = red4[0][t] + red4[1][t] + red4[2][t] + red4[3][t];
    float v1 = red4[0][t + 256] + red4[1][t + 256] + red4[2][t + 256] + red4[3][t + 256];
    atomicAdd(&sout[b * NFLAT + t], v0);
    atomicAdd(&sout[b * NFLAT + t + 256], v1);
}

// out = squash(s2); store fp32 or bf16 per flag
__global__ __launch_bounds__(256) void fin_kernel(const float* __restrict__ s2,
                                                  void* __restrict__ out,
                                                  const int* __restrict__ flagp) {
    const int b = blockIdx.x;
    const int t = threadIdx.x;
    const int fl = *flagp;
    const int j = t >> 4, g = t & 15;
    const int n0 = j * 32 + 2 * g;
    float v0 = s2[b * NFLAT + n0], v1 = s2[b * NFLAT + n0 + 1];
    float p = v0 * v0 + v1 * v1;
    p += __shfl_xor(p, 1); p += __shfl_xor(p, 2);
    p += __shfl_xor(p, 4); p += __shfl_xor(p, 8);
    float sc = (p / (1.f + p)) / sqrtf(p + 1e-7f);
    if (fl) {
        ((u16*)out)[b * NFLAT + n0]     = f2b(sc * v0);
        ((u16*)out)[b * NFLAT + n0 + 1] = f2b(sc * v1);
    } else {
        ((float*)out)[b * NFLAT + n0]     = sc * v0;
        ((float*)out)[b * NFLAT + n0 + 1] = sc * v1;
    }
}

extern "C" void kernel_launch(void* const* d_in, const int* in_sizes, int n_in,
                              void* d_out, int out_size, void* d_ws, size_t ws_size,
                              hipStream_t stream) {
    // Resolve inputs by element count (robust to ordering):
    // inputs = 64*512*128 = 4194304, W = 512*16*128*32 = 33554432.
    const void* x = nullptr;
    const void* W = nullptr;
    for (int a = 0; a < n_in; ++a) {
        if (in_sizes[a] == 64 * 512 * 128) x = d_in[a];
        else if (in_sizes[a] == 512 * 16 * 128 * 32) W = d_in[a];
    }
    if (!x) x = d_in[0];
    if (!W) W = d_in[1];

    char* ws = (char*)d_ws;
    float* s0 = (float*)ws;               // raw sum; scale 1/16 applied at squash
    float* s1 = s0 + 32768;
    float* s2 = s1 + 32768;
    int* flag = (int*)(ws + 3ull * 32768 * sizeof(float));
    u16* uhat = (u16*)(ws + 3ull * 32768 * sizeof(float) + 16);  // 33.5 MB

    hipMemsetAsync(ws, 0, 3ull * 32768 * sizeof(float), stream);
    hipLaunchKernelGGL(probe_kernel, dim3(1), dim3(256), 0, stream, (const u16*)x, flag);
    hipLaunchKernelGGL(gemm_kernel, dim3(2048), dim3(256), 0, stream, x, W, uhat, flag);
    hipLaunchKernelGGL(p0_kernel, dim3(1024), dim3(256), 0, stream, uhat, s0);
    hipLaunchKernelGGL(route_kernel, dim3(1024), dim3(256), 0, stream, uhat, s0, s0, s1, 0);
    hipLaunchKernelGGL(route_kernel, dim3(1024), dim3(256), 0, stream, uhat, s0, s1, s2, 1);
    hipLaunchKernelGGL(fin_kernel, dim3(64), dim3(256), 0, stream, s2, d_out, flag);
}

// Round 6
// 245.429 us; speedup vs baseline: 1.0284x; 1.0284x over previous
//
#include <hip/hip_runtime.h>

typedef unsigned short u16;
typedef unsigned int u32;
typedef unsigned long long u64;
typedef __attribute__((ext_vector_type(8))) short short8;
typedef __attribute__((ext_vector_type(4))) float f32x4;

#define ICAPS 512
#define IDIM 128
#define NFLAT 512  // NCAPS(16) * ODIM(32)

__device__ __forceinline__ float b2f(u16 h) {
    union { u32 u; float f; } x; x.u = ((u32)h) << 16; return x.f;
}
__device__ __forceinline__ u16 f2b(float f) {
    union { float f; u32 u; } x; x.f = f;
    return (u16)((x.u + 0x7FFFu + ((x.u >> 16) & 1u)) >> 16);
}

// ---------------------------------------------------------------------------
// GEMM: u_hat[b,i,n] = sum_k x[b,i,k]*W[i,j(n),k,d(n)], n=j*32+d. fp32 inputs.
// Block: one i, one 128-wide n-chunk. M=64(b), N=128(n), K=128(k).
// A staged in LDS (coalesced float4); W loaded DIRECT to registers per
// fragment column (16-lane groups read 64B segments; line-pairs hit L1).
// W is read exactly once grid-wide. No LDS for W => no bank conflicts,
// 17KB LDS => 4 blocks/CU.
// ---------------------------------------------------------------------------
__global__ __launch_bounds__(256, 4) void gemm_kernel(const float* __restrict__ x,
                                                      const float* __restrict__ W,
                                                      u16* __restrict__ uhat) {
    __shared__ __align__(16) u16 As[64 * 136];   // x[b][k] bf16, pitch 136
    const int i = blockIdx.x >> 2;
    const int chunk = blockIdx.x & 3;
    const int t = threadIdx.x;

    // Stage A: 64 rows x 128 k of x for this i; 2048 float4, 8/thread
    {
        const float4* xa = (const float4*)x;
        float4 av[8];
        #pragma unroll
        for (int l = 0; l < 8; ++l) {
            int id = l * 256 + t;
            av[l] = xa[(size_t)((id >> 5) * ICAPS + i) * 32 + (id & 31)];
        }
        #pragma unroll
        for (int l = 0; l < 8; ++l) {
            int id = l * 256 + t;
            int row = id >> 5, kq = id & 31;
            union { u16 h[4]; u64 q; } pk;
            pk.h[0] = f2b(av[l].x); pk.h[1] = f2b(av[l].y);
            pk.h[2] = f2b(av[l].z); pk.h[3] = f2b(av[l].w);
            *(u64*)&As[row * 136 + kq * 4] = pk.q;
        }
    }
    __syncthreads();

    const int lane = t & 63;
    const int w = t >> 6;
    const int ln = lane & 15;
    const int q = lane >> 4;

    // Per-lane W column base: column c in the 128-wide chunk => j,d
    const float* colbase[2];
    #pragma unroll
    for (int nt = 0; nt < 2; ++nt) {
        int c = (2 * w + nt) * 16 + ln;
        int jj = c >> 5, d = c & 31;
        colbase[nt] = W + (size_t)(i * 16 + chunk * 4 + jj) * 128 * 32 + d;
    }

    f32x4 acc[4][2] = {};
    #pragma unroll
    for (int ks = 0; ks < 4; ++ks) {
        const int ko = ks * 32 + q * 8;
        short8 a[4], bb[2];
        #pragma unroll
        for (int mt = 0; mt < 4; ++mt)
            a[mt] = *(const short8*)&As[(mt * 16 + ln) * 136 + ko];
        #pragma unroll
        for (int nt = 0; nt < 2; ++nt) {
            const float* p = colbase[nt] + (size_t)ko * 32;
            float wv[8];
            #pragma unroll
            for (int e = 0; e < 8; ++e) wv[e] = p[e * 32];   // offset e*128B imm
            #pragma unroll
            for (int e = 0; e < 8; ++e) bb[nt][e] = (short)f2b(wv[e]);
        }
        #pragma unroll
        for (int mt = 0; mt < 4; ++mt)
            #pragma unroll
            for (int nt = 0; nt < 2; ++nt)
                acc[mt][nt] = __builtin_amdgcn_mfma_f32_16x16x32_bf16(a[mt], bb[nt], acc[mt][nt], 0, 0, 0);
    }
    // C/D: col = lane&15, row = q*4 + reg (m89/m91-verified)
    #pragma unroll
    for (int mt = 0; mt < 4; ++mt)
        #pragma unroll
        for (int nt = 0; nt < 2; ++nt) {
            int n = chunk * 128 + (2 * w + nt) * 16 + ln;
            #pragma unroll
            for (int r = 0; r < 4; ++r) {
                int brow = mt * 16 + q * 4 + r;
                uhat[((size_t)brow * ICAPS + i) * NFLAT + n] = f2b(acc[mt][nt][r]);
            }
        }
}

// ---------------------------------------------------------------------------
// p0: q0[bx][n] = sum_{i in slice} uhat[b,i,n]; bx = b*16+ch. No atomics.
// ---------------------------------------------------------------------------
__global__ __launch_bounds__(256) void p0_kernel(const u16* __restrict__ uhat,
                                                 float* __restrict__ q0) {
    __shared__ __align__(16) float red[4][NFLAT];
    const int b = blockIdx.x >> 4;
    const int ch = blockIdx.x & 15;
    const int t = threadIdx.x;
    const int wv = t >> 6, l = t & 63;
    float acc[8] = {0.f, 0.f, 0.f, 0.f, 0.f, 0.f, 0.f, 0.f};
    for (int ii = 0; ii < 8; ++ii) {
        int i = ch * 32 + wv * 8 + ii;
        union { uint4 v; u16 h[8]; } tmp;
        tmp.v = *(const uint4*)&uhat[((size_t)b * ICAPS + i) * NFLAT + l * 8];
        #pragma unroll
        for (int e = 0; e < 8; ++e) acc[e] += b2f(tmp.h[e]);
    }
    #pragma unroll
    for (int e = 0; e < 8; ++e) red[wv][l * 8 + e] = acc[e];
    __syncthreads();
    q0[(size_t)blockIdx.x * NFLAT + t] =
        red[0][t] + red[1][t] + red[2][t] + red[3][t];
    q0[(size_t)blockIdx.x * NFLAT + 256 + t] =
        red[0][t + 256] + red[1][t + 256] + red[2][t + 256] + red[3][t + 256];
}

// combine: s[b][n] = sum_ch q[b*16+ch][n]
__global__ __launch_bounds__(256) void combine_kernel(const float* __restrict__ q,
                                                      float* __restrict__ s) {
    const int b = blockIdx.x, t = threadIdx.x;
    #pragma unroll
    for (int rep = 0; rep < 2; ++rep) {
        int n = rep * 256 + t;
        float acc = 0.f;
        #pragma unroll
        for (int ch = 0; ch < 16; ++ch)
            acc += q[(size_t)(b * 16 + ch) * NFLAT + n];
        s[b * NFLAT + n] = acc;
    }
}

__device__ __forceinline__ void squash_osum(const float* __restrict__ s0,
                                            const float* __restrict__ s1,
                                            float* __restrict__ osum,
                                            int b, int t, int use1) {
    const int j = t >> 4, g = t & 15;   // 16 threads per j, 2 d's each
    const int n0 = j * 32 + 2 * g;
    float v0 = s0[b * NFLAT + n0] * 0.0625f;
    float v1 = s0[b * NFLAT + n0 + 1] * 0.0625f;
    float p = v0 * v0 + v1 * v1;
    p += __shfl_xor(p, 1); p += __shfl_xor(p, 2);
    p += __shfl_xor(p, 4); p += __shfl_xor(p, 8);
    float sc = (p / (1.f + p)) / sqrtf(p + 1e-7f);
    float o0 = sc * v0, o1 = sc * v1;
    if (use1) {
        float w0 = s1[b * NFLAT + n0];
        float w1 = s1[b * NFLAT + n0 + 1];
        float pq = w0 * w0 + w1 * w1;
        pq += __shfl_xor(pq, 1); pq += __shfl_xor(pq, 2);
        pq += __shfl_xor(pq, 4); pq += __shfl_xor(pq, 8);
        float sc1 = (pq / (1.f + pq)) / sqrtf(pq + 1e-7f);
        o0 += sc1 * w0; o1 += sc1 * w1;
    }
    osum[n0] = o0; osum[n0 + 1] = o1;
}

// route: osum = squash(s0/16) (+ squash(s1) if use1); per (b,i) in slice:
// d_j = dot(osum, uhat); c = softmax_j; qout[bx] += c*uhat. No atomics.
__global__ __launch_bounds__(256) void route_kernel(const u16* __restrict__ uhat,
                                                    const float* __restrict__ s0,
                                                    const float* __restrict__ s1,
                                                    float* __restrict__ qout,
                                                    int use1) {
    __shared__ float osum[NFLAT];
    __shared__ __align__(16) float red[4][NFLAT];
    const int b = blockIdx.x >> 4;
    const int ch = blockIdx.x & 15;
    const int t = threadIdx.x;
    squash_osum(s0, s1, osum, b, t, use1);
    __syncthreads();
    const int wv = t >> 6, l = t & 63;
    float os[8], acc[8];
    #pragma unroll
    for (int e = 0; e < 8; ++e) { os[e] = osum[l * 8 + e]; acc[e] = 0.f; }
    for (int ii = 0; ii < 8; ++ii) {
        int i = ch * 32 + wv * 8 + ii;
        union { uint4 v; u16 h[8]; } tmp;
        tmp.v = *(const uint4*)&uhat[((size_t)b * ICAPS + i) * NFLAT + l * 8];
        float u[8];
        #pragma unroll
        for (int e = 0; e < 8; ++e) u[e] = b2f(tmp.h[e]);
        float d = 0.f;
        #pragma unroll
        for (int e = 0; e < 8; ++e) d += u[e] * os[e];
        d += __shfl_xor(d, 1); d += __shfl_xor(d, 2);   // quad = one j
        float mx = d;
        mx = fmaxf(mx, __shfl_xor(mx, 4));  mx = fmaxf(mx, __shfl_xor(mx, 8));
        mx = fmaxf(mx, __shfl_xor(mx, 16)); mx = fmaxf(mx, __shfl_xor(mx, 32));
        float ex = __expf(d - mx);
        float ss = ex;
        ss += __shfl_xor(ss, 4);  ss += __shfl_xor(ss, 8);
        ss += __shfl_xor(ss, 16); ss += __shfl_xor(ss, 32);
        float c = ex / ss;
        #pragma unroll
        for (int e = 0; e < 8; ++e) acc[e] += c * u[e];
    }
    #pragma unroll
    for (int e = 0; e < 8; ++e) red[wv][l * 8 + e] = acc[e];
    __syncthreads();
    qout[(size_t)blockIdx.x * NFLAT + t] =
        red[0][t] + red[1][t] + red[2][t] + red[3][t];
    qout[(size_t)blockIdx.x * NFLAT + 256 + t] =
        red[0][t + 256] + red[1][t + 256] + red[2][t + 256] + red[3][t + 256];
}

// fin: s2[b][n] = sum_ch q2; out = squash(s2), fp32
__global__ __launch_bounds__(256) void fin_kernel(const float* __restrict__ q2,
                                                  float* __restrict__ out) {
    const int b = blockIdx.x, t = threadIdx.x;
    const int j = t >> 4, g = t & 15;
    const int n0 = j * 32 + 2 * g;
    float v0 = 0.f, v1 = 0.f;
    #pragma unroll
    for (int ch = 0; ch < 16; ++ch) {
        v0 += q2[(size_t)(b * 16 + ch) * NFLAT + n0];
        v1 += q2[(size_t)(b * 16 + ch) * NFLAT + n0 + 1];
    }
    float p = v0 * v0 + v1 * v1;
    p += __shfl_xor(p, 1); p += __shfl_xor(p, 2);
    p += __shfl_xor(p, 4); p += __shfl_xor(p, 8);
    float sc = (p / (1.f + p)) / sqrtf(p + 1e-7f);
    out[b * NFLAT + n0]     = sc * v0;
    out[b * NFLAT + n0 + 1] = sc * v1;
}

extern "C" void kernel_launch(void* const* d_in, const int* in_sizes, int n_in,
                              void* d_out, int out_size, void* d_ws, size_t ws_size,
                              hipStream_t stream) {
    // fp32 inputs (established R4). Resolve by element count.
    const float* x = nullptr;
    const float* W = nullptr;
    for (int a = 0; a < n_in; ++a) {
        if (in_sizes[a] == 64 * 512 * 128) x = (const float*)d_in[a];
        else if (in_sizes[a] == 512 * 16 * 128 * 32) W = (const float*)d_in[a];
    }
    if (!x) x = (const float*)d_in[0];
    if (!W) W = (const float*)d_in[1];

    char* ws = (char*)d_ws;
    const size_t U = 2ull * 64 * 512 * 512;          // uhat bytes = 33.5 MB
    u16*   uhat = (u16*)ws;
    float* q0 = (float*)(ws + U);                    // 1024*512 f32 = 2 MB
    float* q1 = (float*)(ws + U + (2ull << 20));
    float* q2 = (float*)(ws + U + (4ull << 20));
    float* s0 = (float*)(ws + U + (6ull << 20));     // 64*512 f32 = 128 KB
    float* s1 = (float*)(ws + U + (6ull << 20) + (128ull << 10));
    float* out = (float*)d_out;

    hipLaunchKernelGGL(gemm_kernel, dim3(2048), dim3(256), 0, stream, x, W, uhat);
    hipLaunchKernelGGL(p0_kernel, dim3(1024), dim3(256), 0, stream, uhat, q0);
    hipLaunchKernelGGL(combine_kernel, dim3(64), dim3(256), 0, stream, q0, s0);
    hipLaunchKernelGGL(route_kernel, dim3(1024), dim3(256), 0, stream, uhat, s0, s0, q1, 0);
    hipLaunchKernelGGL(combine_kernel, dim3(64), dim3(256), 0, stream, q1, s1);
    hipLaunchKernelGGL(route_kernel, dim3(1024), dim3(256), 0, stream, uhat, s0, s1, q2, 1);
    hipLaunchKernelGGL(fin_kernel, dim3(64), dim3(256), 0, stream, q2, out);
}